// Round 11
// baseline (50.745 us; speedup 1.0000x reference)
//
#include <hip/hip_runtime.h>
#include <math.h>

// FocalCTCloss — MI355X (gfx950)
// T=160, N=128, C=6625, S=32, L=2S+1=65, blank=0
// R11: R7's proven 3-kernel skeleton + T-MAJOR gather order.
//   All previous gathers were n-major (block walks one sample: consecutive
//   accesses jump 3.4MB between t-rows => every access a fresh DRAM page;
//   ~34-38us regardless of CU count => page-activation bound). T-major
//   sweeps (t,n,j) lexicographically: the device walks log_probs
//   sequentially at 0.5% density, per-t accesses cluster in one 3.4MB slab,
//   per-(n,t) 33 labels cluster in one 26.5KB row. ws writes coalesced
//   [t][n][j]; scan kernel stages 132B strided runs from MALL-hot ws,
//   hidden by the chunk pipeline. R10 lesson: single-kernel finalization
//   regressed (same-address RMW serialization) — kernel-boundary handoff.

#define TT 160
#define NN 128
#define CC 6625
#define SS 32
#define JJ 33              // unique labels per (n,t): blank + 32
#define NTJ (TT * JJ)      // 5280 per sample
#define NJ  (NN * JJ)      // 4224 per t
#define CHT 32             // t-steps per chunk
#define CHE (CHT * JJ)     // 1056 floats per chunk
#define NCH 5
#define NEGV  (-1e30f)
#define LOG2E 1.4426950408889634f
#define LN2   0.6931471805599453f

// wave64 shift-up-by-1 via DPP: row_shr:1 + row_bcast15 patch for lanes 16k.
// Lane 0 result is garbage — callers mask explicitly.
__device__ __forceinline__ float dpp_up1(float x, bool row0lane) {
    int xi = __float_as_int(x);
    int shr = __builtin_amdgcn_update_dpp(xi, xi, 0x111, 0xf, 0xf, false); // row_shr:1
    int bc  = __builtin_amdgcn_update_dpp(xi, xi, 0x142, 0xf, 0xf, false); // row_bcast15
    return __int_as_float(row0lane ? bc : shr);
}

// ---------------- Kernel A: t-major gather, coalesced ws write ----------------
__global__ __launch_bounds__(256) void gather_tmajor_kernel(
    const float* __restrict__ log_probs,   // [T, N, C]
    const int*   __restrict__ targets,     // [N, S]
    float*       __restrict__ lp_ws)       // [T][N][J], log2-scaled
{
    const int g = blockIdx.x * 256 + threadIdx.x;   // 0 .. T*N*J-1 (grid exact)
    const int t = g / NJ;
    const int r = g - t * NJ;
    const int n = r / JJ;
    const int j = r - n * JJ;
    const int label = j ? targets[n * SS + j - 1] : 0;   // targets: 16KB, L2-hot
    lp_ws[g] = log_probs[(size_t)t * (NN * CC) + (size_t)n * CC + label] * LOG2E;
}

// ---------------- Kernel B: stage-from-ws + DPP scan (pipelined) ----------------
__global__ __launch_bounds__(1024) void scan_kernel(
    const float* __restrict__ lp_ws,          // [T][N][J]
    const int*   __restrict__ targets,        // [N, S]
    const int*   __restrict__ input_lengths,  // [N]
    const int*   __restrict__ target_lengths, // [N]
    float*       __restrict__ per_sample)     // [N]
{
    const int n   = blockIdx.x;
    const int tid = threadIdx.x;

    __shared__ float lp[NTJ];       // [160][33] = 21.1 KB
    __shared__ int   lab[JJ];

    if (tid < JJ) lab[tid] = (tid == 0) ? 0 : targets[n * SS + tid - 1];

    // stage chunk 0 (t = 0..31): element (tt,j) from lp_ws[tt*NJ + n*JJ + j]
    {
        const int i = tid;                  // 1024 threads, 1056 elements
        if (i < CHE) {
            const int tt = i / JJ;
            const int j  = i - tt * JJ;
            lp[i] = lp_ws[(size_t)tt * NJ + n * JJ + j];
        }
        if (tid < CHE - 1024) {             // remaining 32
            const int i2 = tid + 1024;
            const int tt = i2 / JJ;
            const int j  = i2 - tt * JJ;
            lp[i2] = lp_ws[(size_t)tt * NJ + n * JJ + j];
        }
    }
    __syncthreads();

    // ---- scan state (wave 0) ----
    const int lane = tid;
    const int tl = target_lengths[n];
    const int Lv = 2 * tl + 1;
    const int slot = (lane & 1) ? (1 + (lane >> 1)) : 0;
    const bool skip = (lane & 1) && (lane >= 3) &&
                      (lab[1 + (lane >> 1)] != lab[lane >> 1]);
    const bool validl   = lane < Lv;
    const bool valid64  = 64 < Lv;
    const bool row0lane = (lane & 15) == 0;

    float v = NEGV;
    if (lane == 0) v = lp[0];                   // t=0, blank
    if (lane == 1) v = lp[1];                   // t=0, first label
    float e = NEGV;                             // l=64 rides on lane 63

    const int ilen = input_lengths[n];
    const int Tlim = (ilen < TT) ? ilen : TT;

    for (int c = 0; c < NCH; ++c) {
        // waves 1..15: stage chunk c+1 from ws (MALL-hot, 132B runs)
        if (tid >= 64 && c + 1 < NCH) {
            const int base = (c + 1) * CHE;
#pragma unroll
            for (int k = 0; k < 2; ++k) {
                const int r = (tid - 64) + k * 960;
                if (r < CHE) {
                    const int i  = base + r;
                    const int tt = i / JJ;
                    const int j  = i - tt * JJ;
                    lp[i] = lp_ws[(size_t)tt * NJ + n * JJ + j];
                }
            }
        }
        // wave 0: scan chunk c
        if (tid < 64) {
            const int t_lo = (c == 0) ? 1 : c * CHT;
            int t_hi = (c + 1) * CHT;
            if (t_hi > Tlim) t_hi = Tlim;
            for (int t = t_lo; t < t_hi; ++t) {
                const float u1 = dpp_up1(v, row0lane);   // v[lane-1]
                const float u2 = dpp_up1(u1, row0lane);  // v[lane-2]
                const float a2 = (lane == 0) ? NEGV : u1;
                const float a3 = skip ? u2 : NEGV;

                const float lpt64 = lp[t * JJ];          // blank slot, broadcast
                const float me = fmaxf(e, v);
                const float ne = me + log2f(exp2f(e - me) + exp2f(v - me)) + lpt64;

                const float m  = fmaxf(v, fmaxf(a2, a3));
                const float nv = m + log2f(exp2f(v - m) + exp2f(a2 - m) + exp2f(a3 - m))
                                   + lp[t * JJ + slot];

                v = validl  ? nv : NEGV;
                e = valid64 ? ne : NEGV;
            }
        }
        __syncthreads();
    }

    if (tid >= 64) return;

    const int i1 = 2 * tl;
    const int i2 = 2 * tl - 1;
    const float A1 = (i1 == 64) ? __shfl(e, 63) : __shfl(v, i1);
    const float A2 = __shfl(v, i2);
    if (lane == 0) {
        const float m = fmaxf(A1, A2);
        float loss = -LN2 * (m + log2f(exp2f(A1 - m) + exp2f(A2 - m)));
        if (loss > 1e29f) loss = 0.0f;           // zero_infinity
        per_sample[n] = loss / (float)tl;
    }
}

// ---------------- Kernel C: reduce + focal ----------------
__global__ __launch_bounds__(128) void focal_reduce_kernel(
    const float* __restrict__ per_sample, float* __restrict__ out)
{
    __shared__ float s[NN];
    int tid = threadIdx.x;
    s[tid] = per_sample[tid];
    __syncthreads();
    for (int off = NN / 2; off > 0; off >>= 1) {
        if (tid < off) s[tid] += s[tid + off];
        __syncthreads();
    }
    if (tid == 0) {
        float mean = s[0] / (float)NN;
        float pp = expf(-mean);
        float om = 1.0f - pp;
        out[0] = 0.5f * om * om * mean;          // ALPHA=0.5, GAMMA=2.0
    }
}

extern "C" void kernel_launch(void* const* d_in, const int* in_sizes, int n_in,
                              void* d_out, int out_size, void* d_ws, size_t ws_size,
                              hipStream_t stream) {
    const float* log_probs      = (const float*)d_in[0];
    const int*   targets        = (const int*)d_in[1];
    const int*   input_lengths  = (const int*)d_in[2];
    const int*   target_lengths = (const int*)d_in[3];
    float* out = (float*)d_out;

    float* per_sample = (float*)d_ws;                       // 128 floats
    float* lp_ws      = (float*)((char*)d_ws + 1024);       // T*N*J floats (2.7 MB)

    gather_tmajor_kernel<<<(TT * NJ) / 256, 256, 0, stream>>>(log_probs, targets, lp_ws);
    scan_kernel<<<NN, 1024, 0, stream>>>(lp_ws, targets, input_lengths,
                                         target_lengths, per_sample);
    focal_reduce_kernel<<<1, NN, 0, stream>>>(per_sample, out);
}

// Round 12
// 39.775 us; speedup vs baseline: 1.2758x; 1.2758x over previous
//
#include <hip/hip_runtime.h>
#include <math.h>

// FocalCTCloss — MI355X (gfx950)
// T=160, N=128, C=6625, S=32, L=2S+1=65, blank=0
// R12: restore R6 (best, 39.7us) + two structure-preserving shavings:
//   (a) uneven chunks 36/36/36/36/16 -> exposed final scan tail halved;
//   (b) one-wave shuffle reduce kernel (fixed-order butterfly).
// Evidence basis: gather is the device random-128B-line floor (~655K lines,
// ~80MB, ~2.3 TB/s effective): order-independent (R7 n-major == R11 t-major
// == 50.7 split), CU-count independent (R6 128CU fused == R7 256CU split
// gather time), request-count insensitive (R2->R3). Closed: split kernels
// (+11us), spin handoff (+47us R5), RMW finalization (+7us R10).
// Structure: per-sample block; waves 1-15 gather chunk c+1's 33 unique
// log-probs/t into LDS while wave 0 runs the DPP-shift alpha recursion over
// chunk c (log2 domain, native v_exp/v_log). One barrier per chunk.

#define TT 160
#define NN 128
#define CC 6625
#define SS 32
#define JJ 33              // unique labels per (n,t): blank + 32
#define NTJ (TT * JJ)      // 5280
#define NCH 5              // chunks: [0,36,72,108,144,160)
#define NEGV  (-1e30f)
#define LOG2E 1.4426950408889634f
#define LN2   0.6931471805599453f

// wave64 shift-up-by-1 via DPP: row_shr:1 + row_bcast15 patch for lanes 16k.
// Lane 0 result is garbage — callers mask explicitly.
__device__ __forceinline__ float dpp_up1(float x, bool row0lane) {
    int xi = __float_as_int(x);
    int shr = __builtin_amdgcn_update_dpp(xi, xi, 0x111, 0xf, 0xf, false); // row_shr:1
    int bc  = __builtin_amdgcn_update_dpp(xi, xi, 0x142, 0xf, 0xf, false); // row_bcast15
    return __int_as_float(row0lane ? bc : shr);
}

__global__ __launch_bounds__(1024) void ctc_fused_kernel(
    const float* __restrict__ log_probs,      // [T, N, C]
    const int*   __restrict__ targets,        // [N, S]
    const int*   __restrict__ input_lengths,  // [N]
    const int*   __restrict__ target_lengths, // [N]
    float*       __restrict__ per_sample)     // [N]
{
    const int n   = blockIdx.x;
    const int tid = threadIdx.x;

    __shared__ float lp[NTJ];       // 21.1 KB, log2-scaled unique columns
    __shared__ int   lab[JJ];       // slot 0 = blank, slot j = targets[j-1]

    if (tid < JJ) lab[tid] = (tid == 0) ? 0 : targets[n * SS + tid - 1];
    __syncthreads();

    const size_t rowbase = (size_t)n * CC;

    // ---- prologue: gather chunk 0 (t = 0..35, 1188 elems), all 1024 thr ----
#pragma unroll
    for (int k = 0; k < 2; ++k) {
        const int i = tid + k * 1024;
        if (i < 36 * JJ) {
            const int t = i / JJ;
            const int j = i - t * JJ;
            lp[i] = log_probs[(size_t)t * (NN * CC) + rowbase + lab[j]] * LOG2E;
        }
    }
    __syncthreads();

    // ---- scan state (wave 0) ----
    const int lane = tid;                       // used only when tid < 64
    const int tl = target_lengths[n];
    const int Lv = 2 * tl + 1;
    const int slot = (lane & 1) ? (1 + (lane >> 1)) : 0;
    const bool skip = (lane & 1) && (lane >= 3) &&
                      (lab[1 + (lane >> 1)] != lab[lane >> 1]);
    const bool validl   = lane < Lv;
    const bool valid64  = 64 < Lv;
    const bool row0lane = (lane & 15) == 0;

    float v = NEGV;
    if (lane == 0) v = lp[0];                   // t=0, blank
    if (lane == 1) v = lp[1];                   // t=0, first label
    float e = NEGV;                             // l=64 rides on lane 63

    const int ilen = input_lengths[n];
    const int Tlim = (ilen < TT) ? ilen : TT;

    // ---- pipelined chunks: waves 1..15 gather c+1, wave 0 scans c ----
    // chunk c spans t in [36c, min(36(c+1),160))
    for (int c = 0; c < NCH; ++c) {
        if (tid >= 64 && c + 1 < NCH) {
            const int ts   = 36 * (c + 1);
            const int te   = (36 * (c + 2) < TT) ? 36 * (c + 2) : TT;
            const int base = ts * JJ;
            const int cnt  = (te - ts) * JJ;            // 1188 or 528
#pragma unroll
            for (int k = 0; k < 2; ++k) {
                const int r = (tid - 64) + k * 960;
                if (r < cnt) {
                    const int i = base + r;
                    const int t = i / JJ;
                    const int j = i - t * JJ;
                    lp[i] = log_probs[(size_t)t * (NN * CC) + rowbase + lab[j]] * LOG2E;
                }
            }
        }
        if (tid < 64) {
            const int t_lo = (c == 0) ? 1 : 36 * c;
            int t_hi = 36 * (c + 1);
            if (t_hi > Tlim) t_hi = Tlim;
            for (int t = t_lo; t < t_hi; ++t) {
                const float u1 = dpp_up1(v, row0lane);   // v[lane-1]
                const float u2 = dpp_up1(u1, row0lane);  // v[lane-2]
                const float a2 = (lane == 0) ? NEGV : u1;
                const float a3 = skip ? u2 : NEGV;

                const float lpt64 = lp[t * JJ];          // blank slot, broadcast
                const float me = fmaxf(e, v);
                const float ne = me + log2f(exp2f(e - me) + exp2f(v - me)) + lpt64;

                const float m  = fmaxf(v, fmaxf(a2, a3));
                const float nv = m + log2f(exp2f(v - m) + exp2f(a2 - m) + exp2f(a3 - m))
                                   + lp[t * JJ + slot];

                v = validl  ? nv : NEGV;
                e = valid64 ? ne : NEGV;
            }
        }
        __syncthreads();
    }

    if (tid >= 64) return;

    const int i1 = 2 * tl;
    const int i2 = 2 * tl - 1;
    const float A1 = (i1 == 64) ? __shfl(e, 63) : __shfl(v, i1);
    const float A2 = __shfl(v, i2);
    if (lane == 0) {
        const float m = fmaxf(A1, A2);
        float loss = -LN2 * (m + log2f(exp2f(A1 - m) + exp2f(A2 - m)));
        if (loss > 1e29f) loss = 0.0f;           // zero_infinity
        per_sample[n] = loss / (float)tl;
    }
}

// ---------------- Kernel 2: one-wave reduce + focal ----------------
__global__ __launch_bounds__(64) void focal_reduce_kernel(
    const float* __restrict__ per_sample, float* __restrict__ out)
{
    const int lane = threadIdx.x;
    float s = per_sample[lane] + per_sample[lane + 64];
    // deterministic butterfly (fixed pattern/order every call)
    for (int off = 32; off > 0; off >>= 1)
        s += __shfl_xor(s, off);
    if (lane == 0) {
        const float mean = s / (float)NN;
        const float pp = __expf(-mean);
        const float om = 1.0f - pp;
        out[0] = 0.5f * om * om * mean;          // ALPHA=0.5, GAMMA=2.0
    }
}

extern "C" void kernel_launch(void* const* d_in, const int* in_sizes, int n_in,
                              void* d_out, int out_size, void* d_ws, size_t ws_size,
                              hipStream_t stream) {
    const float* log_probs      = (const float*)d_in[0];
    const int*   targets        = (const int*)d_in[1];
    const int*   input_lengths  = (const int*)d_in[2];
    const int*   target_lengths = (const int*)d_in[3];
    float* out        = (float*)d_out;
    float* per_sample = (float*)d_ws;    // 128 floats

    ctc_fused_kernel<<<NN, 1024, 0, stream>>>(log_probs, targets, input_lengths,
                                              target_lengths, per_sample);
    focal_reduce_kernel<<<1, 64, 0, stream>>>(per_sample, out);
}